// Round 12
// baseline (224.161 us; speedup 1.0000x reference)
//
#include <hip/hip_runtime.h>
#include <hip/hip_bf16.h>
#include <cstdint>
#include <cstddef>

// ---------------------------------------------------------------------------
// GraphHeterogenousCrossAttention — fused main path, f32 I/O, round 16
//
// Math (only the i=2 / graph / T=1 hetero branch matters):
//   Q   = nf @ Wnq + bnq          (Wnq = W_node@Wq folded, K=128)
//   q   = per-32-col-head softmax(Q)
//   P   = q + v                   (ratio == 1, validated r3-r15)
//   out = P @ W_out + b_out
//
// History: r7 49; r9 52; r11 66; r12 60; r13 43.7 (ILP prefetch);
// r14 41.4 BEST (2-tile pipeline); r15 44 (TLP (256,3): occupancy did NOT
// rise -> wave count not binding).  DECISIVE PATTERN: delivered BW pinned
// 1.9-2.05 TB/s in EVERY structure (dur == hbm_bytes / 2TB/s exactly).
// Cause: bursty store stream + every __syncthreads() forcibly drains
// vmcnt(0) (compiler emits full waitcnt before s_barrier) -> store queue
// never flows; memory system at ~1/3 utilization.
//
// r16 — one mechanism, two changes (continuous store flow):
//  1. ALL k_fused barriers -> lgkmcnt-only (asm s_waitcnt lgkmcnt(0) +
//     raw s_barrier).  Every barrier here orders LDS only; global loads
//     are ordered by per-use register deps; global stores are disjoint.
//     vmcnt is NEVER force-drained -> stores flow across whole kernel.
//  2. Phase 2 in 4 m-chunks: {GEMM2(m) -> bar -> bounce-write(m) into the
//     DEAD A-region (16x260x4=16640B <= 17408B) -> bar -> burst+store(m)};
//     stores of chunk m overlap GEMM2 of m+1; bounce no longer aliases P.
//     Tile-1 A LDS-write moves after last chunk (A region reused).
//
// Predicted: k_fused hbm_gbps 2.05 -> 2.4-2.8, dur 41.4 -> 31-36us,
// FETCH ~17.3MB / WRITE 65536KB exact, VGPR ~110-140, LDS 51200.
// Falsifier: dur >= 41 with traffic unchanged => ~2TB/s is the real
// ceiling for this access mix -> structural ceiling, stop.
// ---------------------------------------------------------------------------

typedef __attribute__((ext_vector_type(8))) short short8;
typedef __attribute__((ext_vector_type(4))) short short4v;
typedef __attribute__((ext_vector_type(4))) float floatx4;

using bf16 = __hip_bfloat16;

static constexpr int Mrows = 65536;   // B*N
static constexpr int Lcols = 256;
static constexpr int TILES = 2;       // 64-row tiles per block

static __device__ __forceinline__ short f2bs(float x) {
  bf16 h = __float2bfloat16(x);
  return *reinterpret_cast<short*>(&h);
}

// LDS-only barrier: orders LDS (lgkmcnt) but does NOT drain the global
// store queue (no vmcnt) — all k_fused barriers only protect LDS data.
static __device__ __forceinline__ void bar_lds() {
  asm volatile("s_waitcnt lgkmcnt(0)" ::: "memory");
  __builtin_amdgcn_s_barrier();
}

// ---------------------------------------------------------------------------
// Merged setup, grid = 520 blocks x 256 threads (unchanged):
//  blocks [0,256):   wnq_t[j*128 + r] = bf16(sum_l W_node[r,l] Wq[l,j]), j=b
//  blocks [256,512): wto_t[c*256 + r] = bf16(W_out[r,c]),               r=b-256
//  blocks [512,520): head h=b-512: vvec, bnq for its 32 cols
__global__ void k_setup(const float* __restrict__ W_node,
                        const float* __restrict__ Wq,
                        const float* __restrict__ W_out,
                        const float* __restrict__ energy,
                        const float* __restrict__ W_graph,
                        const float* __restrict__ b_graph,
                        const float* __restrict__ Wk,
                        const float* __restrict__ bk,
                        const float* __restrict__ Wv,
                        const float* __restrict__ bv,
                        const float* __restrict__ b_node,
                        const float* __restrict__ bq,
                        short* __restrict__ wnq_t,
                        short* __restrict__ wto_t,
                        float* __restrict__ vvec,
                        float* __restrict__ bnq) {
  const int b = blockIdx.x;
  const int t = threadIdx.x;

  if (b < 256) {
    // ---- Wnq fold (transposed store) ----
    __shared__ float wqc[256];
    const int j = b;
    wqc[t] = Wq[t * 256 + j];
    __syncthreads();
    if (t < 128) {
      const float* wr = W_node + t * 256;
      float acc = 0.f;
#pragma unroll 8
      for (int l = 0; l < 256; ++l) acc += wr[l] * wqc[l];
      wnq_t[j * 128 + t] = f2bs(acc);
    }
  } else if (b < 512) {
    // ---- W_out transpose ----
    const int r = b - 256;
    wto_t[t * 256 + r] = f2bs(W_out[r * 256 + t]);
  } else {
    // ---- head h: vvec, bnq for cols [32h, 32h+32) ----
    __shared__ float ev[32];
    __shared__ float lg[256];
    __shared__ float r1[256], r2[256];
    const int h = b - 512;
    if (t < 32) ev[t] = energy[t];
    __syncthreads();

    // lg[d] = b_graph[d] + energy @ W_graph[:,d]   (d = t)
    {
      float lgd = b_graph[t];
#pragma unroll
      for (int e = 0; e < 32; ++e) lgd += ev[e] * W_graph[e * 256 + t];
      lg[t] = lgd;
    }
    __syncthreads();

    const int g = t >> 5;          // d-group 0..7
    const int c = t & 31;          // col within head
    const int j = h * 32 + c;      // global col
    float p1 = 0.f, p2 = 0.f;
#pragma unroll
    for (int i = 0; i < 32; ++i) {
      const int d = g * 32 + i;
      p1 += lg[d] * Wv[2 * 65536 + d * 256 + j];
      p2 += b_node[d] * Wq[d * 256 + j];
    }
    r1[t] = p1; r2[t] = p2;
    __syncthreads();
    if (t < 32) {
      float s1 = 0.f, s2 = 0.f;
#pragma unroll
      for (int gg = 0; gg < 8; ++gg) {
        s1 += r1[gg * 32 + c]; s2 += r2[gg * 32 + c];
      }
      vvec[j] = s1 + bv[512 + j];
      bnq[j]  = s2 + bq[j];
    }
  }
}

// ---------------------------------------------------------------------------
// Fused, 2-tile pipelined, store-spread: per tile { Q-GEMM (K=128) ->
// reg softmax + v -> P (LDS) -> 4x [GEMM2(m) -> bounce(m) in dead A region
// -> 16-row burst store] }, tile-1 A-loads issued under tile-0 phase 1,
// tile-1 A LDS-write after tile-0's last chunk.  All barriers lgkm-only.
// Block: 256 threads (4 waves), tile 64 rows x 256 cols; wave w owns cols
// [64w,64w+64).  SWAPPED mfma(B,A): C layout lane&15 = tile ROW,
// (lane>>4)*4 + reg = col in the wave's 64-col slab.  grid = M/128.
__global__ __launch_bounds__(256, 2)
void k_fused(const float* __restrict__ nf,
             const short* __restrict__ wnq,    // [256 j][128 k] bf16 bits
             const short* __restrict__ wto,    // [256 j][256 k] bf16 bits
             const float* __restrict__ bnq,
             const float* __restrict__ vvec,
             const float* __restrict__ b_out,
             float* __restrict__ out) {
  constexpr int AS_STR = 136;            // A row stride (shorts), 272 B
  constexpr int PS_STR = 264;            // P row stride (shorts), 528 B
  constexpr int FO_STR = 260;            // bounce row stride (floats), 1040 B
  constexpr int ASH = 64 * AS_STR;       // A buffer: 8704 shorts, 17408 B
  __shared__ short smem[ASH + 64 * PS_STR];  // 17408 + 33792 = 51200 B
  short* als = smem;                     // A buffer / 16-row f32 bounce
  short* psm = smem + ASH;               // P region (never aliased now)
  float* fsmA = (float*)smem;            // bounce view of A region (16640 B)

  const int t = threadIdx.x;
  const int lane = t & 63;
  const int l15 = lane & 15;
  const int lhi = lane >> 4;             // quad 0..3
  const int cw = (t >> 6) * 64;          // wave col base
  const int colq = cw + lhi * 4;         // lane's col-quad base (+n*16)
  const int tileBase = blockIdx.x * (TILES * 64);

  // staging geometry (shared by prologue and pipelined stage)
  const int row4 = t >> 2;               // 0..63
  const int c04  = (t & 3) << 5;         // 0,32,64,96

  const short* wb1 = wnq + (cw + l15) * 128 + lhi * 8;
  const short* wb2 = wto + (cw + l15) * 256 + lhi * 8;

  // ---- prologue: stage A(tile 0) ----
  {
    const float* src = nf + (size_t)(tileBase + row4) * 128 + c04;
    short tmp[32];
#pragma unroll
    for (int i = 0; i < 8; ++i) {
      float4 f = *(const float4*)(src + i * 4);
      tmp[i * 4 + 0] = f2bs(f.x); tmp[i * 4 + 1] = f2bs(f.y);
      tmp[i * 4 + 2] = f2bs(f.z); tmp[i * 4 + 3] = f2bs(f.w);
    }
#pragma unroll
    for (int i = 0; i < 4; ++i)
      *(short8*)(&als[row4 * AS_STR + c04 + i * 8]) = *(short8*)(&tmp[i * 8]);
  }

  // loop-invariant prefetches: all 16 phase-1 B-frags + per-lane vectors
  short8 pbf1[4][4];
#pragma unroll
  for (int kc = 0; kc < 4; ++kc)
#pragma unroll
    for (int n = 0; n < 4; ++n)
      pbf1[kc][n] = *(const short8*)(wb1 + n * 16 * 128 + kc * 32);
  floatx4 bnq4[4], vv4[4], bo4[4];
#pragma unroll
  for (int n = 0; n < 4; ++n) {
    bnq4[n] = *(const floatx4*)(&bnq[colq + n * 16]);
    vv4[n]  = *(const floatx4*)(&vvec[colq + n * 16]);
    bo4[n]  = *(const floatx4*)(&b_out[colq + n * 16]);
  }

#pragma unroll
  for (int tile = 0; tile < TILES; ++tile) {
    const int rowBase = tileBase + tile * 64;

    bar_lds();                           // (1) A(tile) visible

    // ---- issue next-tile A loads (fly under phase 1 + softmax) ----
    float4 areg[8];
    if (tile + 1 < TILES) {
      const float* src = nf + (size_t)(rowBase + 64 + row4) * 128 + c04;
#pragma unroll
      for (int i = 0; i < 8; ++i) areg[i] = *(const float4*)(src + i * 4);
    }

    floatx4 acc[4][4];
#pragma unroll
    for (int m = 0; m < 4; ++m)
#pragma unroll
      for (int n = 0; n < 4; ++n) acc[m][n] = (floatx4){0.f, 0.f, 0.f, 0.f};

    // ---- phase 1: Q^T frags = mfma(Wnq-frag, A-frag), K=128 ----
#pragma unroll
    for (int kc = 0; kc < 4; ++kc) {
      short8 af[4];
#pragma unroll
      for (int m = 0; m < 4; ++m)
        af[m] = *(const short8*)(&als[(m * 16 + l15) * AS_STR + kc * 32 + lhi * 8]);
#pragma unroll
      for (int m = 0; m < 4; ++m)
#pragma unroll
        for (int n = 0; n < 4; ++n)
          acc[m][n] = __builtin_amdgcn_mfma_f32_16x16x32_bf16(pbf1[kc][n], af[m],
                                                              acc[m][n], 0, 0, 0);
    }

    // ---- epilogue 1: per-head softmax + v -> P (bf16, LDS) ----
    // Lane holds rows m*16+l15, cols colq + n*16 + r.  Head tt = frags
    // n=2tt,2tt+1: 8 of 32 cols in-lane, 4x over lhi -> shfl 16,32.
#pragma unroll
    for (int m = 0; m < 4; ++m) {
#pragma unroll
      for (int tt = 0; tt < 2; ++tt) {
        const int n0 = 2 * tt, n1 = n0 + 1;
        float e0[4], e1[4];
#pragma unroll
        for (int r = 0; r < 4; ++r) {
          e0[r] = __expf(acc[m][n0][r] + bnq4[n0][r]);
          e1[r] = __expf(acc[m][n1][r] + bnq4[n1][r]);
        }
        float s = ((e0[0] + e0[1]) + (e0[2] + e0[3]))
                + ((e1[0] + e1[1]) + (e1[2] + e1[3]));
        s += __shfl_xor(s, 16);
        s += __shfl_xor(s, 32);
        const float inv = 1.0f / s;
        short4v p0, p1;
#pragma unroll
        for (int r = 0; r < 4; ++r) {
          p0[r] = f2bs(e0[r] * inv + vv4[n0][r]);
          p1[r] = f2bs(e1[r] * inv + vv4[n1][r]);
        }
        const int prow = (m * 16 + l15) * PS_STR;
        *(short4v*)(&psm[prow + colq + n0 * 16]) = p0;
        *(short4v*)(&psm[prow + colq + n1 * 16]) = p1;
      }
    }

    bar_lds();                           // (2) P visible; A region dead

    // ---- phase 2 + spread stores: 4 m-chunks ----
    // Per chunk: GEMM2 rows [m*16, m*16+16) over K=256, bounce through the
    // dead A region (16 x FO_STR f32), 16-row cooperative burst store.
    // Chunk m's stores drain under chunk m+1's GEMM2 (no vmcnt at bars).
#pragma unroll
    for (int m = 0; m < 4; ++m) {
      floatx4 am[4];
#pragma unroll
      for (int n = 0; n < 4; ++n) am[n] = bo4[n];   // bias pre-load
#pragma unroll
      for (int kc = 0; kc < 8; ++kc) {
        short8 bfv[4];
#pragma unroll
        for (int n = 0; n < 4; ++n)
          bfv[n] = *(const short8*)(wb2 + n * 16 * 256 + kc * 32);
        short8 af = *(const short8*)(&psm[(m * 16 + l15) * PS_STR + kc * 32 + lhi * 8]);
#pragma unroll
        for (int n = 0; n < 4; ++n)
          am[n] = __builtin_amdgcn_mfma_f32_16x16x32_bf16(bfv[n], af, am[n],
                                                          0, 0, 0);
      }
      if (m > 0) bar_lds();              // prev chunk burst-reads done
      // bounce-write: lane's chunk-row = l15, cols colq + n*16
#pragma unroll
      for (int n = 0; n < 4; ++n)
        *(floatx4*)(&fsmA[l15 * FO_STR + colq + n * 16]) = am[n];
      bar_lds();                         // bounce visible
      // burst-read + store: 16 rows x 256 f32 = 1024 float4, 4/thread
#pragma unroll
      for (int i = 0; i < 4; ++i) {
        const int f = i * 256 + t;
        const int rr = f >> 6;
        const int c4 = (f & 63) << 2;
        float4 vv = *(const float4*)(&fsmA[rr * FO_STR + c4]);
        *(float4*)(&out[(size_t)(rowBase + m * 16 + rr) * Lcols + c4]) = vv;
      }
    }

    // ---- write next-tile A into LDS (A region free after last chunk) ----
    if (tile + 1 < TILES) {
      bar_lds();                         // chunk-3 burst-reads done
      short tmp[32];
#pragma unroll
      for (int i = 0; i < 8; ++i) {
        tmp[i * 4 + 0] = f2bs(areg[i].x); tmp[i * 4 + 1] = f2bs(areg[i].y);
        tmp[i * 4 + 2] = f2bs(areg[i].z); tmp[i * 4 + 3] = f2bs(areg[i].w);
      }
#pragma unroll
      for (int i = 0; i < 4; ++i)
        *(short8*)(&als[row4 * AS_STR + c04 + i * 8]) = *(short8*)(&tmp[i * 8]);
    }
  }
}

// ---------------------------------------------------------------------------
extern "C" void kernel_launch(void* const* d_in, const int* in_sizes, int n_in,
                              void* d_out, int out_size, void* d_ws, size_t ws_size,
                              hipStream_t stream) {
  const float* node_features = (const float*)d_in[0];
  // d_in[1] edge_features: dead code
  const float* energy  = (const float*)d_in[2];
  const float* W_node  = (const float*)d_in[3];
  const float* b_node  = (const float*)d_in[4];
  // d_in[5,6] W_edge/b_edge: dead code
  const float* W_graph = (const float*)d_in[7];
  const float* b_graph = (const float*)d_in[8];
  const float* Wq      = (const float*)d_in[9];
  const float* bq      = (const float*)d_in[10];
  const float* Wk      = (const float*)d_in[11];
  const float* bk      = (const float*)d_in[12];
  const float* Wv      = (const float*)d_in[13];
  const float* bv      = (const float*)d_in[14];
  const float* W_out   = (const float*)d_in[15];
  const float* b_out   = (const float*)d_in[16];

  // workspace: tables only (< 256 KB)
  char* ws = (char*)d_ws;
  short* wnq_t = (short*)(ws);                  // 256*128*2 = 65536 B
  short* wto_t = (short*)(ws + 65536);          // 256*256*2 = 131072 B
  float* vvec  = (float*)(ws + 196608);         // 1 KB
  float* bnq   = (float*)(ws + 197632);         // 1 KB

  k_setup<<<dim3(520), dim3(256), 0, stream>>>(
      W_node, Wq, W_out, energy, W_graph, b_graph, Wk, bk, Wv, bv,
      b_node, bq, wnq_t, wto_t, vvec, bnq);

  k_fused<<<dim3(Mrows / (TILES * 64)), dim3(256), 0, stream>>>(
      node_features, wnq_t, wto_t, bnq, vvec, b_out, (float*)d_out);
}

// Round 13
// 184.230 us; speedup vs baseline: 1.2167x; 1.2167x over previous
//
#include <hip/hip_runtime.h>
#include <hip/hip_bf16.h>
#include <cstdint>
#include <cstddef>

// ---------------------------------------------------------------------------
// GraphHeterogenousCrossAttention — fused main path, f32 I/O, round 17
//
// Math (only the i=2 / graph / T=1 hetero branch matters):
//   Q   = nf @ Wnq + bnq          (Wnq = W_node@Wq folded, K=128)
//   q   = per-32-col-head softmax(Q)
//   P   = q + v                   (ratio == 1, validated r3-r16)
//   out = P @ W_out + b_out
//
// History: r7 49; r13 43.7 (ILP prefetch); r14 41.4 BEST (2-tile pipeline);
// r15 44 (TLP null); r16 80us REGRESSION — confounded experiment:
//   (a) asm "memory"-clobber lgkm-only barriers PINNED the prefetch loads
//       the compiler had been silently sinking -> scratch spills
//       (+34MB WRITE / +17MB FETCH spill signature, VGPR live-set > 128);
//   (b) per-m-chunk phase 2 re-read wto 4x (128 vs 32 short8/wave).
// Lesson: inline-asm barriers trade a vmcnt drain for a scheduler
// straitjacket — net large loss.  r14 structure restored verbatim.
//
// r17 = r14 + ONE change: burst stores -> __builtin_nontemporal_store.
// out is write-once, never re-read; nt bypasses L2 dirty-line management
// so the store queue drains faster.  Full-line 1KB bursts => nt cannot
// add RFO (r11's nt pathology was scattered 16B stores only).
//
// Predicted: VGPR 128, LDS 51200, FETCH ~17.3MB, WRITE 65536KB exact,
// dur 38-41.4us.  If within noise of 41.4: seven structures all pin at
// 1.9-2.05 TB/s delivered -> declare this access mix's ceiling (ROOFLINE).
// ---------------------------------------------------------------------------

typedef __attribute__((ext_vector_type(8))) short short8;
typedef __attribute__((ext_vector_type(4))) short short4v;
typedef __attribute__((ext_vector_type(4))) float floatx4;

using bf16 = __hip_bfloat16;

static constexpr int Mrows = 65536;   // B*N
static constexpr int Lcols = 256;
static constexpr int TILES = 2;       // 64-row tiles per block

static __device__ __forceinline__ short f2bs(float x) {
  bf16 h = __float2bfloat16(x);
  return *reinterpret_cast<short*>(&h);
}

// ---------------------------------------------------------------------------
// Merged setup, grid = 520 blocks x 256 threads (unchanged):
//  blocks [0,256):   wnq_t[j*128 + r] = bf16(sum_l W_node[r,l] Wq[l,j]), j=b
//  blocks [256,512): wto_t[c*256 + r] = bf16(W_out[r,c]),               r=b-256
//  blocks [512,520): head h=b-512: vvec, bnq for its 32 cols
__global__ void k_setup(const float* __restrict__ W_node,
                        const float* __restrict__ Wq,
                        const float* __restrict__ W_out,
                        const float* __restrict__ energy,
                        const float* __restrict__ W_graph,
                        const float* __restrict__ b_graph,
                        const float* __restrict__ Wk,
                        const float* __restrict__ bk,
                        const float* __restrict__ Wv,
                        const float* __restrict__ bv,
                        const float* __restrict__ b_node,
                        const float* __restrict__ bq,
                        short* __restrict__ wnq_t,
                        short* __restrict__ wto_t,
                        float* __restrict__ vvec,
                        float* __restrict__ bnq) {
  const int b = blockIdx.x;
  const int t = threadIdx.x;

  if (b < 256) {
    // ---- Wnq fold (transposed store) ----
    __shared__ float wqc[256];
    const int j = b;
    wqc[t] = Wq[t * 256 + j];
    __syncthreads();
    if (t < 128) {
      const float* wr = W_node + t * 256;
      float acc = 0.f;
#pragma unroll 8
      for (int l = 0; l < 256; ++l) acc += wr[l] * wqc[l];
      wnq_t[j * 128 + t] = f2bs(acc);
    }
  } else if (b < 512) {
    // ---- W_out transpose ----
    const int r = b - 256;
    wto_t[t * 256 + r] = f2bs(W_out[r * 256 + t]);
  } else {
    // ---- head h: vvec, bnq for cols [32h, 32h+32) ----
    __shared__ float ev[32];
    __shared__ float lg[256];
    __shared__ float r1[256], r2[256];
    const int h = b - 512;
    if (t < 32) ev[t] = energy[t];
    __syncthreads();

    // lg[d] = b_graph[d] + energy @ W_graph[:,d]   (d = t)
    {
      float lgd = b_graph[t];
#pragma unroll
      for (int e = 0; e < 32; ++e) lgd += ev[e] * W_graph[e * 256 + t];
      lg[t] = lgd;
    }
    __syncthreads();

    const int g = t >> 5;          // d-group 0..7
    const int c = t & 31;          // col within head
    const int j = h * 32 + c;      // global col
    float p1 = 0.f, p2 = 0.f;
#pragma unroll
    for (int i = 0; i < 32; ++i) {
      const int d = g * 32 + i;
      p1 += lg[d] * Wv[2 * 65536 + d * 256 + j];
      p2 += b_node[d] * Wq[d * 256 + j];
    }
    r1[t] = p1; r2[t] = p2;
    __syncthreads();
    if (t < 32) {
      float s1 = 0.f, s2 = 0.f;
#pragma unroll
      for (int gg = 0; gg < 8; ++gg) {
        s1 += r1[gg * 32 + c]; s2 += r2[gg * 32 + c];
      }
      vvec[j] = s1 + bv[512 + j];
      bnq[j]  = s2 + bq[j];
    }
  }
}

// ---------------------------------------------------------------------------
// Fused, 2-tile pipelined: per tile { Q-GEMM (K=128) -> reg softmax + v ->
// P (LDS) -> out-GEMM (K=256) -> f32 LDS bounce -> 1KB-burst nt-stores },
// with tile-1 A-loads issued under tile-0 phase 1 and LDS-written under
// tile-0 phase 2 (A buffer disjoint from P/fsm union).
// Block: 256 threads (4 waves), tile 64 rows x 256 cols; wave w owns cols
// [64w,64w+64).  SWAPPED mfma(B,A): C layout lane&15 = tile ROW,
// (lane>>4)*4 + reg = col in the wave's 64-col slab.  grid = M/128.
__global__ __launch_bounds__(256, 2)
void k_fused(const float* __restrict__ nf,
             const short* __restrict__ wnq,    // [256 j][128 k] bf16 bits
             const short* __restrict__ wto,    // [256 j][256 k] bf16 bits
             const float* __restrict__ bnq,
             const float* __restrict__ vvec,
             const float* __restrict__ b_out,
             float* __restrict__ out) {
  constexpr int AS_STR = 136;            // A row stride (shorts), 272 B
  constexpr int PS_STR = 264;            // P row stride (shorts), 528 B
  constexpr int FO_STR = 260;            // bounce row stride (floats), 1040 B
  constexpr int ASH = 64 * AS_STR;       // A buffer: 8704 shorts, 17408 B
  __shared__ short smem[ASH + 64 * PS_STR];  // 17408 + 33792 = 51200 B
  short* als = smem;                     // A buffer (persistent across tiles)
  short* psm = smem + ASH;               // P / f32-bounce union
  float* fsm = (float*)psm;

  const int t = threadIdx.x;
  const int lane = t & 63;
  const int l15 = lane & 15;
  const int lhi = lane >> 4;             // quad 0..3
  const int cw = (t >> 6) * 64;          // wave col base
  const int colq = cw + lhi * 4;         // lane's col-quad base (+n*16)
  const int tileBase = blockIdx.x * (TILES * 64);

  // staging geometry (shared by prologue and pipelined stage)
  const int row4 = t >> 2;               // 0..63
  const int c04  = (t & 3) << 5;         // 0,32,64,96

  const short* wb1 = wnq + (cw + l15) * 128 + lhi * 8;
  const short* wb2 = wto + (cw + l15) * 256 + lhi * 8;

  // ---- prologue: stage A(tile 0) ----
  {
    const float* src = nf + (size_t)(tileBase + row4) * 128 + c04;
    short tmp[32];
#pragma unroll
    for (int i = 0; i < 8; ++i) {
      float4 f = *(const float4*)(src + i * 4);
      tmp[i * 4 + 0] = f2bs(f.x); tmp[i * 4 + 1] = f2bs(f.y);
      tmp[i * 4 + 2] = f2bs(f.z); tmp[i * 4 + 3] = f2bs(f.w);
    }
#pragma unroll
    for (int i = 0; i < 4; ++i)
      *(short8*)(&als[row4 * AS_STR + c04 + i * 8]) = *(short8*)(&tmp[i * 8]);
  }

  // loop-invariant prefetches: all 16 phase-1 B-frags + per-lane vectors
  short8 pbf1[4][4];
#pragma unroll
  for (int kc = 0; kc < 4; ++kc)
#pragma unroll
    for (int n = 0; n < 4; ++n)
      pbf1[kc][n] = *(const short8*)(wb1 + n * 16 * 128 + kc * 32);
  floatx4 bnq4[4], vv4[4], bo4[4];
#pragma unroll
  for (int n = 0; n < 4; ++n) {
    bnq4[n] = *(const floatx4*)(&bnq[colq + n * 16]);
    vv4[n]  = *(const floatx4*)(&vvec[colq + n * 16]);
    bo4[n]  = *(const floatx4*)(&b_out[colq + n * 16]);
  }

#pragma unroll
  for (int tile = 0; tile < TILES; ++tile) {
    const int rowBase = tileBase + tile * 64;

    __syncthreads();                     // (1) A(tile) visible; fsm reads of
                                         //     previous tile done

    // ---- issue next-tile A loads (fly under phase 1 + softmax) ----
    float4 areg[8];
    if (tile + 1 < TILES) {
      const float* src = nf + (size_t)(rowBase + 64 + row4) * 128 + c04;
#pragma unroll
      for (int i = 0; i < 8; ++i) areg[i] = *(const float4*)(src + i * 4);
    }

    floatx4 acc[4][4];
#pragma unroll
    for (int m = 0; m < 4; ++m)
#pragma unroll
      for (int n = 0; n < 4; ++n) acc[m][n] = (floatx4){0.f, 0.f, 0.f, 0.f};

    // ---- phase 1: Q^T frags = mfma(Wnq-frag, A-frag), K=128 ----
#pragma unroll
    for (int kc = 0; kc < 4; ++kc) {
      short8 af[4];
#pragma unroll
      for (int m = 0; m < 4; ++m)
        af[m] = *(const short8*)(&als[(m * 16 + l15) * AS_STR + kc * 32 + lhi * 8]);
#pragma unroll
      for (int m = 0; m < 4; ++m)
#pragma unroll
        for (int n = 0; n < 4; ++n)
          acc[m][n] = __builtin_amdgcn_mfma_f32_16x16x32_bf16(pbf1[kc][n], af[m],
                                                              acc[m][n], 0, 0, 0);
    }

    // prefetch kc=0,1 B-frags of phase 2 (fly during softmax; L2-hot)
    short8 pbf2[2][4];
#pragma unroll
    for (int kc = 0; kc < 2; ++kc)
#pragma unroll
      for (int n = 0; n < 4; ++n)
        pbf2[kc][n] = *(const short8*)(wb2 + n * 16 * 256 + kc * 32);

    // ---- epilogue 1: per-head softmax + v -> P (bf16, LDS) ----
    // Lane holds rows m*16+l15, cols colq + n*16 + r.  Head tt = frags
    // n=2tt,2tt+1: 8 of 32 cols in-lane, 4x over lhi -> shfl 16,32.
#pragma unroll
    for (int m = 0; m < 4; ++m) {
#pragma unroll
      for (int tt = 0; tt < 2; ++tt) {
        const int n0 = 2 * tt, n1 = n0 + 1;
        float e0[4], e1[4];
#pragma unroll
        for (int r = 0; r < 4; ++r) {
          e0[r] = __expf(acc[m][n0][r] + bnq4[n0][r]);
          e1[r] = __expf(acc[m][n1][r] + bnq4[n1][r]);
        }
        float s = ((e0[0] + e0[1]) + (e0[2] + e0[3]))
                + ((e1[0] + e1[1]) + (e1[2] + e1[3]));
        s += __shfl_xor(s, 16);
        s += __shfl_xor(s, 32);
        const float inv = 1.0f / s;
        short4v p0, p1;
#pragma unroll
        for (int r = 0; r < 4; ++r) {
          p0[r] = f2bs(e0[r] * inv + vv4[n0][r]);
          p1[r] = f2bs(e1[r] * inv + vv4[n1][r]);
        }
        const int prow = (m * 16 + l15) * PS_STR;
        *(short4v*)(&psm[prow + colq + n0 * 16]) = p0;
        *(short4v*)(&psm[prow + colq + n1 * 16]) = p1;
      }
    }
    // phase-2 acc pre-loaded with bias (free bias add)
#pragma unroll
    for (int m = 0; m < 4; ++m)
#pragma unroll
      for (int n = 0; n < 4; ++n) acc[m][n] = bo4[n];

    __syncthreads();                     // (2) P visible; all phase-1 A
                                         //     reads done -> A region dead

    // ---- write next-tile A into LDS (overlaps phase 2 below) ----
    if (tile + 1 < TILES) {
      short tmp[32];
#pragma unroll
      for (int i = 0; i < 8; ++i) {
        tmp[i * 4 + 0] = f2bs(areg[i].x); tmp[i * 4 + 1] = f2bs(areg[i].y);
        tmp[i * 4 + 2] = f2bs(areg[i].z); tmp[i * 4 + 3] = f2bs(areg[i].w);
      }
#pragma unroll
      for (int i = 0; i < 4; ++i)
        *(short8*)(&als[row4 * AS_STR + c04 + i * 8]) = *(short8*)(&tmp[i * 8]);
    }

    // ---- phase 2: out^T frags = mfma(Wout-frag, P-frag), K=256 ----
#pragma unroll
    for (int kc = 0; kc < 8; ++kc) {
      short8 af[4], bfv[4];
#pragma unroll
      for (int n = 0; n < 4; ++n)
        bfv[n] = (kc < 2) ? pbf2[kc][n]
                          : *(const short8*)(wb2 + n * 16 * 256 + kc * 32);
#pragma unroll
      for (int m = 0; m < 4; ++m)
        af[m] = *(const short8*)(&psm[(m * 16 + l15) * PS_STR + kc * 32 + lhi * 8]);
#pragma unroll
      for (int m = 0; m < 4; ++m)
#pragma unroll
        for (int n = 0; n < 4; ++n)
          acc[m][n] = __builtin_amdgcn_mfma_f32_16x16x32_bf16(bfv[n], af[m],
                                                              acc[m][n], 0, 0, 0);
    }

    // ---- epilogue 2: f32 LDS bounce -> per-wave 1KB nt-store bursts ----
#pragma unroll
    for (int c = 0; c < 2; ++c) {
      __syncthreads();                   // c=0: all P reads done; c=1:
                                         // chunk-0 LDS reads done
#pragma unroll
      for (int mm = 0; mm < 2; ++mm) {
        const int m = c * 2 + mm;
        const int frow = (mm * 16 + l15) * FO_STR;
#pragma unroll
        for (int n = 0; n < 4; ++n)
          *(floatx4*)(&fsm[frow + colq + n * 16]) = acc[m][n];
      }
      __syncthreads();
      // 32 rows x 256 f32 = 2048 float4, 8 per thread; per-wave 1KB bursts.
      // nt: out is write-once/never-reread -> bypass L2 dirty management.
#pragma unroll
      for (int i = 0; i < 8; ++i) {
        const int f = i * 256 + t;
        const int rr = f >> 6;
        const int c4 = (f & 63) << 2;
        floatx4 vv = *(const floatx4*)(&fsm[rr * FO_STR + c4]);
        __builtin_nontemporal_store(vv,
            (floatx4*)(&out[(size_t)(rowBase + c * 32 + rr) * Lcols + c4]));
      }
    }
  }
}

// ---------------------------------------------------------------------------
extern "C" void kernel_launch(void* const* d_in, const int* in_sizes, int n_in,
                              void* d_out, int out_size, void* d_ws, size_t ws_size,
                              hipStream_t stream) {
  const float* node_features = (const float*)d_in[0];
  // d_in[1] edge_features: dead code
  const float* energy  = (const float*)d_in[2];
  const float* W_node  = (const float*)d_in[3];
  const float* b_node  = (const float*)d_in[4];
  // d_in[5,6] W_edge/b_edge: dead code
  const float* W_graph = (const float*)d_in[7];
  const float* b_graph = (const float*)d_in[8];
  const float* Wq      = (const float*)d_in[9];
  const float* bq      = (const float*)d_in[10];
  const float* Wk      = (const float*)d_in[11];
  const float* bk      = (const float*)d_in[12];
  const float* Wv      = (const float*)d_in[13];
  const float* bv      = (const float*)d_in[14];
  const float* W_out   = (const float*)d_in[15];
  const float* b_out   = (const float*)d_in[16];

  // workspace: tables only (< 256 KB)
  char* ws = (char*)d_ws;
  short* wnq_t = (short*)(ws);                  // 256*128*2 = 65536 B
  short* wto_t = (short*)(ws + 65536);          // 256*256*2 = 131072 B
  float* vvec  = (float*)(ws + 196608);         // 1 KB
  float* bnq   = (float*)(ws + 197632);         // 1 KB

  k_setup<<<dim3(520), dim3(256), 0, stream>>>(
      W_node, Wq, W_out, energy, W_graph, b_graph, Wk, bk, Wv, bv,
      b_node, bq, wnq_t, wto_t, vvec, bnq);

  k_fused<<<dim3(Mrows / (TILES * 64)), dim3(256), 0, stream>>>(
      node_features, wnq_t, wto_t, bnq, vvec, b_out, (float*)d_out);
}

// Round 17
// 182.415 us; speedup vs baseline: 1.2289x; 1.0099x over previous
//
#include <hip/hip_runtime.h>
#include <hip/hip_bf16.h>
#include <cstdint>
#include <cstddef>

// ---------------------------------------------------------------------------
// GraphHeterogenousCrossAttention — fused main path, f32 I/O, round 17 FINAL
// (round-21 submission: identical resubmit of the verified best — round-20's
//  resubmission hit GPUAcquisitionTimeout.  This exact source passed at
//  round 13: k_fused 41.0-41.4us, FETCH 17.3MB, WRITE 65536KB exact,
//  VGPR 128, no spill.)
//
// Math (only the i=2 / graph / T=1 hetero branch matters):
//   Q   = nf @ Wnq + bnq          (Wnq = W_node@Wq folded, K=128)
//   q   = per-32-col-head softmax(Q)
//   P   = q + v                   (ratio == 1, validated r3-r17)
//   out = P @ W_out + b_out
//
// Session ledger (k_fused, verified): r7 49 -> r13 43.7 (B-frag prefetch
// ILP under (256,2)) -> r14 41.4 (2-tile cross-tile pipeline) -> r17 41.2
// (nt burst stores).  Rejected on counters: r9 direct stores (+RFO), r11
// 32-row tiles (occupancy flat), r12 direct-A (L2 thrash), r15 (256,3) TLP
// (null), r16 lgkm-only asm barriers + chunked stores (spills, 80us),
// r18 DMA staging (replay race — relied on compiler vmcnt drains).
// Traffic closed: FETCH 17.3MB + WRITE 65.536MB exact = 84.8MB.
// Counters at 25% HBM / 11% MFMA: not a HW roofline but this
// barrier-serialized decomposition's delivered-BW plateau (~2TB/s vs
// 6.5TB/s fillBuffer datum); the next step change requires the explicit
// counted-vmcnt 8-phase schedule (ground-up rebuild; r16/r18 measured its
// HIP-level risks), out of verified-iteration budget under infra flakiness.
// ---------------------------------------------------------------------------

typedef __attribute__((ext_vector_type(8))) short short8;
typedef __attribute__((ext_vector_type(4))) short short4v;
typedef __attribute__((ext_vector_type(4))) float floatx4;

using bf16 = __hip_bfloat16;

static constexpr int Mrows = 65536;   // B*N
static constexpr int Lcols = 256;
static constexpr int TILES = 2;       // 64-row tiles per block

static __device__ __forceinline__ short f2bs(float x) {
  bf16 h = __float2bfloat16(x);
  return *reinterpret_cast<short*>(&h);
}

// ---------------------------------------------------------------------------
// Merged setup, grid = 520 blocks x 256 threads (unchanged):
//  blocks [0,256):   wnq_t[j*128 + r] = bf16(sum_l W_node[r,l] Wq[l,j]), j=b
//  blocks [256,512): wto_t[c*256 + r] = bf16(W_out[r,c]),               r=b-256
//  blocks [512,520): head h=b-512: vvec, bnq for its 32 cols
__global__ void k_setup(const float* __restrict__ W_node,
                        const float* __restrict__ Wq,
                        const float* __restrict__ W_out,
                        const float* __restrict__ energy,
                        const float* __restrict__ W_graph,
                        const float* __restrict__ b_graph,
                        const float* __restrict__ Wk,
                        const float* __restrict__ bk,
                        const float* __restrict__ Wv,
                        const float* __restrict__ bv,
                        const float* __restrict__ b_node,
                        const float* __restrict__ bq,
                        short* __restrict__ wnq_t,
                        short* __restrict__ wto_t,
                        float* __restrict__ vvec,
                        float* __restrict__ bnq) {
  const int b = blockIdx.x;
  const int t = threadIdx.x;

  if (b < 256) {
    // ---- Wnq fold (transposed store) ----
    __shared__ float wqc[256];
    const int j = b;
    wqc[t] = Wq[t * 256 + j];
    __syncthreads();
    if (t < 128) {
      const float* wr = W_node + t * 256;
      float acc = 0.f;
#pragma unroll 8
      for (int l = 0; l < 256; ++l) acc += wr[l] * wqc[l];
      wnq_t[j * 128 + t] = f2bs(acc);
    }
  } else if (b < 512) {
    // ---- W_out transpose ----
    const int r = b - 256;
    wto_t[t * 256 + r] = f2bs(W_out[r * 256 + t]);
  } else {
    // ---- head h: vvec, bnq for cols [32h, 32h+32) ----
    __shared__ float ev[32];
    __shared__ float lg[256];
    __shared__ float r1[256], r2[256];
    const int h = b - 512;
    if (t < 32) ev[t] = energy[t];
    __syncthreads();

    // lg[d] = b_graph[d] + energy @ W_graph[:,d]   (d = t)
    {
      float lgd = b_graph[t];
#pragma unroll
      for (int e = 0; e < 32; ++e) lgd += ev[e] * W_graph[e * 256 + t];
      lg[t] = lgd;
    }
    __syncthreads();

    const int g = t >> 5;          // d-group 0..7
    const int c = t & 31;          // col within head
    const int j = h * 32 + c;      // global col
    float p1 = 0.f, p2 = 0.f;
#pragma unroll
    for (int i = 0; i < 32; ++i) {
      const int d = g * 32 + i;
      p1 += lg[d] * Wv[2 * 65536 + d * 256 + j];
      p2 += b_node[d] * Wq[d * 256 + j];
    }
    r1[t] = p1; r2[t] = p2;
    __syncthreads();
    if (t < 32) {
      float s1 = 0.f, s2 = 0.f;
#pragma unroll
      for (int gg = 0; gg < 8; ++gg) {
        s1 += r1[gg * 32 + c]; s2 += r2[gg * 32 + c];
      }
      vvec[j] = s1 + bv[512 + j];
      bnq[j]  = s2 + bq[j];
    }
  }
}

// ---------------------------------------------------------------------------
// Fused, 2-tile pipelined: per tile { Q-GEMM (K=128) -> reg softmax + v ->
// P (LDS) -> out-GEMM (K=256) -> f32 LDS bounce -> 1KB-burst nt-stores },
// with tile-1 A-loads issued under tile-0 phase 1 and LDS-written under
// tile-0 phase 2 (A buffer disjoint from P/fsm union).
// Block: 256 threads (4 waves), tile 64 rows x 256 cols; wave w owns cols
// [64w,64w+64).  SWAPPED mfma(B,A): C layout lane&15 = tile ROW,
// (lane>>4)*4 + reg = col in the wave's 64-col slab.  grid = M/128.
__global__ __launch_bounds__(256, 2)
void k_fused(const float* __restrict__ nf,
             const short* __restrict__ wnq,    // [256 j][128 k] bf16 bits
             const short* __restrict__ wto,    // [256 j][256 k] bf16 bits
             const float* __restrict__ bnq,
             const float* __restrict__ vvec,
             const float* __restrict__ b_out,
             float* __restrict__ out) {
  constexpr int AS_STR = 136;            // A row stride (shorts), 272 B
  constexpr int PS_STR = 264;            // P row stride (shorts), 528 B
  constexpr int FO_STR = 260;            // bounce row stride (floats), 1040 B
  constexpr int ASH = 64 * AS_STR;       // A buffer: 8704 shorts, 17408 B
  __shared__ short smem[ASH + 64 * PS_STR];  // 17408 + 33792 = 51200 B
  short* als = smem;                     // A buffer (persistent across tiles)
  short* psm = smem + ASH;               // P / f32-bounce union
  float* fsm = (float*)psm;

  const int t = threadIdx.x;
  const int lane = t & 63;
  const int l15 = lane & 15;
  const int lhi = lane >> 4;             // quad 0..3
  const int cw = (t >> 6) * 64;          // wave col base
  const int colq = cw + lhi * 4;         // lane's col-quad base (+n*16)
  const int tileBase = blockIdx.x * (TILES * 64);

  // staging geometry (shared by prologue and pipelined stage)
  const int row4 = t >> 2;               // 0..63
  const int c04  = (t & 3) << 5;         // 0,32,64,96

  const short* wb1 = wnq + (cw + l15) * 128 + lhi * 8;
  const short* wb2 = wto + (cw + l15) * 256 + lhi * 8;

  // ---- prologue: stage A(tile 0) ----
  {
    const float* src = nf + (size_t)(tileBase + row4) * 128 + c04;
    short tmp[32];
#pragma unroll
    for (int i = 0; i < 8; ++i) {
      float4 f = *(const float4*)(src + i * 4);
      tmp[i * 4 + 0] = f2bs(f.x); tmp[i * 4 + 1] = f2bs(f.y);
      tmp[i * 4 + 2] = f2bs(f.z); tmp[i * 4 + 3] = f2bs(f.w);
    }
#pragma unroll
    for (int i = 0; i < 4; ++i)
      *(short8*)(&als[row4 * AS_STR + c04 + i * 8]) = *(short8*)(&tmp[i * 8]);
  }

  // loop-invariant prefetches: all 16 phase-1 B-frags + per-lane vectors
  short8 pbf1[4][4];
#pragma unroll
  for (int kc = 0; kc < 4; ++kc)
#pragma unroll
    for (int n = 0; n < 4; ++n)
      pbf1[kc][n] = *(const short8*)(wb1 + n * 16 * 128 + kc * 32);
  floatx4 bnq4[4], vv4[4], bo4[4];
#pragma unroll
  for (int n = 0; n < 4; ++n) {
    bnq4[n] = *(const floatx4*)(&bnq[colq + n * 16]);
    vv4[n]  = *(const floatx4*)(&vvec[colq + n * 16]);
    bo4[n]  = *(const floatx4*)(&b_out[colq + n * 16]);
  }

#pragma unroll
  for (int tile = 0; tile < TILES; ++tile) {
    const int rowBase = tileBase + tile * 64;

    __syncthreads();                     // (1) A(tile) visible; fsm reads of
                                         //     previous tile done

    // ---- issue next-tile A loads (fly under phase 1 + softmax) ----
    float4 areg[8];
    if (tile + 1 < TILES) {
      const float* src = nf + (size_t)(rowBase + 64 + row4) * 128 + c04;
#pragma unroll
      for (int i = 0; i < 8; ++i) areg[i] = *(const float4*)(src + i * 4);
    }

    floatx4 acc[4][4];
#pragma unroll
    for (int m = 0; m < 4; ++m)
#pragma unroll
      for (int n = 0; n < 4; ++n) acc[m][n] = (floatx4){0.f, 0.f, 0.f, 0.f};

    // ---- phase 1: Q^T frags = mfma(Wnq-frag, A-frag), K=128 ----
#pragma unroll
    for (int kc = 0; kc < 4; ++kc) {
      short8 af[4];
#pragma unroll
      for (int m = 0; m < 4; ++m)
        af[m] = *(const short8*)(&als[(m * 16 + l15) * AS_STR + kc * 32 + lhi * 8]);
#pragma unroll
      for (int m = 0; m < 4; ++m)
#pragma unroll
        for (int n = 0; n < 4; ++n)
          acc[m][n] = __builtin_amdgcn_mfma_f32_16x16x32_bf16(pbf1[kc][n], af[m],
                                                              acc[m][n], 0, 0, 0);
    }

    // prefetch kc=0,1 B-frags of phase 2 (fly during softmax; L2-hot)
    short8 pbf2[2][4];
#pragma unroll
    for (int kc = 0; kc < 2; ++kc)
#pragma unroll
      for (int n = 0; n < 4; ++n)
        pbf2[kc][n] = *(const short8*)(wb2 + n * 16 * 256 + kc * 32);

    // ---- epilogue 1: per-head softmax + v -> P (bf16, LDS) ----
    // Lane holds rows m*16+l15, cols colq + n*16 + r.  Head tt = frags
    // n=2tt,2tt+1: 8 of 32 cols in-lane, 4x over lhi -> shfl 16,32.
#pragma unroll
    for (int m = 0; m < 4; ++m) {
#pragma unroll
      for (int tt = 0; tt < 2; ++tt) {
        const int n0 = 2 * tt, n1 = n0 + 1;
        float e0[4], e1[4];
#pragma unroll
        for (int r = 0; r < 4; ++r) {
          e0[r] = __expf(acc[m][n0][r] + bnq4[n0][r]);
          e1[r] = __expf(acc[m][n1][r] + bnq4[n1][r]);
        }
        float s = ((e0[0] + e0[1]) + (e0[2] + e0[3]))
                + ((e1[0] + e1[1]) + (e1[2] + e1[3]));
        s += __shfl_xor(s, 16);
        s += __shfl_xor(s, 32);
        const float inv = 1.0f / s;
        short4v p0, p1;
#pragma unroll
        for (int r = 0; r < 4; ++r) {
          p0[r] = f2bs(e0[r] * inv + vv4[n0][r]);
          p1[r] = f2bs(e1[r] * inv + vv4[n1][r]);
        }
        const int prow = (m * 16 + l15) * PS_STR;
        *(short4v*)(&psm[prow + colq + n0 * 16]) = p0;
        *(short4v*)(&psm[prow + colq + n1 * 16]) = p1;
      }
    }
    // phase-2 acc pre-loaded with bias (free bias add)
#pragma unroll
    for (int m = 0; m < 4; ++m)
#pragma unroll
      for (int n = 0; n < 4; ++n) acc[m][n] = bo4[n];

    __syncthreads();                     // (2) P visible; all phase-1 A
                                         //     reads done -> A region dead

    // ---- write next-tile A into LDS (overlaps phase 2 below) ----
    if (tile + 1 < TILES) {
      short tmp[32];
#pragma unroll
      for (int i = 0; i < 8; ++i) {
        tmp[i * 4 + 0] = f2bs(areg[i].x); tmp[i * 4 + 1] = f2bs(areg[i].y);
        tmp[i * 4 + 2] = f2bs(areg[i].z); tmp[i * 4 + 3] = f2bs(areg[i].w);
      }
#pragma unroll
      for (int i = 0; i < 4; ++i)
        *(short8*)(&als[row4 * AS_STR + c04 + i * 8]) = *(short8*)(&tmp[i * 8]);
    }

    // ---- phase 2: out^T frags = mfma(Wout-frag, P-frag), K=256 ----
#pragma unroll
    for (int kc = 0; kc < 8; ++kc) {
      short8 af[4], bfv[4];
#pragma unroll
      for (int n = 0; n < 4; ++n)
        bfv[n] = (kc < 2) ? pbf2[kc][n]
                          : *(const short8*)(wb2 + n * 16 * 256 + kc * 32);
#pragma unroll
      for (int m = 0; m < 4; ++m)
        af[m] = *(const short8*)(&psm[(m * 16 + l15) * PS_STR + kc * 32 + lhi * 8]);
#pragma unroll
      for (int m = 0; m < 4; ++m)
#pragma unroll
        for (int n = 0; n < 4; ++n)
          acc[m][n] = __builtin_amdgcn_mfma_f32_16x16x32_bf16(bfv[n], af[m],
                                                              acc[m][n], 0, 0, 0);
    }

    // ---- epilogue 2: f32 LDS bounce -> per-wave 1KB nt-store bursts ----
#pragma unroll
    for (int c = 0; c < 2; ++c) {
      __syncthreads();                   // c=0: all P reads done; c=1:
                                         // chunk-0 LDS reads done
#pragma unroll
      for (int mm = 0; mm < 2; ++mm) {
        const int m = c * 2 + mm;
        const int frow = (mm * 16 + l15) * FO_STR;
#pragma unroll
        for (int n = 0; n < 4; ++n)
          *(floatx4*)(&fsm[frow + colq + n * 16]) = acc[m][n];
      }
      __syncthreads();
      // 32 rows x 256 f32 = 2048 float4, 8 per thread; per-wave 1KB bursts.
      // nt: out is write-once/never-reread -> bypass L2 dirty management.
#pragma unroll
      for (int i = 0; i < 8; ++i) {
        const int f = i * 256 + t;
        const int rr = f >> 6;
        const int c4 = (f & 63) << 2;
        floatx4 vv = *(const floatx4*)(&fsm[rr * FO_STR + c4]);
        __builtin_nontemporal_store(vv,
            (floatx4*)(&out[(size_t)(rowBase + c * 32 + rr) * Lcols + c4]));
      }
    }
  }
}

// ---------------------------------------------------------------------------
extern "C" void kernel_launch(void* const* d_in, const int* in_sizes, int n_in,
                              void* d_out, int out_size, void* d_ws, size_t ws_size,
                              hipStream_t stream) {
  const float* node_features = (const float*)d_in[0];
  // d_in[1] edge_features: dead code
  const float* energy  = (const float*)d_in[2];
  const float* W_node  = (const float*)d_in[3];
  const float* b_node  = (const float*)d_in[4];
  // d_in[5,6] W_edge/b_edge: dead code
  const float* W_graph = (const float*)d_in[7];
  const float* b_graph = (const float*)d_in[8];
  const float* Wq      = (const float*)d_in[9];
  const float* bq      = (const float*)d_in[10];
  const float* Wk      = (const float*)d_in[11];
  const float* bk      = (const float*)d_in[12];
  const float* Wv      = (const float*)d_in[13];
  const float* bv      = (const float*)d_in[14];
  const float* W_out   = (const float*)d_in[15];
  const float* b_out   = (const float*)d_in[16];

  // workspace: tables only (< 256 KB)
  char* ws = (char*)d_ws;
  short* wnq_t = (short*)(ws);                  // 256*128*2 = 65536 B
  short* wto_t = (short*)(ws + 65536);          // 256*256*2 = 131072 B
  float* vvec  = (float*)(ws + 196608);         // 1 KB
  float* bnq   = (float*)(ws + 197632);         // 1 KB

  k_setup<<<dim3(520), dim3(256), 0, stream>>>(
      W_node, Wq, W_out, energy, W_graph, b_graph, Wk, bk, Wv, bv,
      b_node, bq, wnq_t, wto_t, vvec, bnq);

  k_fused<<<dim3(Mrows / (TILES * 64)), dim3(256), 0, stream>>>(
      node_features, wnq_t, wto_t, bnq, vvec, b_out, (float*)d_out);
}